// Round 1
// baseline (121.941 us; speedup 1.0000x reference)
//
#include <hip/hip_runtime.h>
#include <math.h>

// Problem constants (from reference)
#define BB 8
#define HH 1024
#define DD 4
#define TI 16
#define TJ 16

__global__ __launch_bounds__(256) void kuramoto_kernel(
    const float* __restrict__ theta, const float* __restrict__ gamma,
    const float* __restrict__ A, const float* __restrict__ omega,
    const float* __restrict__ kappa, const float* __restrict__ alpha,
    float* __restrict__ out)
{
    const int b  = blockIdx.x / (HH / TI);
    const int i0 = (blockIdx.x % (HH / TI)) * TI;
    const int t  = threadIdx.x;
    const int ti = t >> 4;   // 0..15  -> which i row in tile
    const int tj = t & 15;   // 0..15  -> which j col in tile

    __shared__ float tA [TI][TJ + 1];   // A[b, i0+r, j0+c]
    __shared__ float tAT[TJ][TI + 1];   // A[b, j0+r, i0+c]
    __shared__ float tAl[TI][TJ + 1];   // alpha[i0+r, j0+c]
    __shared__ float th_j[TJ][DD];
    __shared__ float th_i[TI][DD];

    // stage theta_i once (64 floats)
    if (t < TI * DD) {
        int ii = t / DD, d = t % DD;
        th_i[ii][d] = theta[(b * HH + i0 + ii) * DD + d];
    }
    __syncthreads();

    float my_thi[DD];
    #pragma unroll
    for (int d = 0; d < DD; ++d) my_thi[d] = th_i[ti][d];

    float acc[DD] = {0.f, 0.f, 0.f, 0.f};

    const float* Ab = A + (size_t)b * HH * HH;

    for (int j0 = 0; j0 < HH; j0 += TJ) {
        __syncthreads();   // protect tiles from previous iteration
        // coalesced tile loads (rows of 16 floats)
        tA [ti][tj] = Ab[(size_t)(i0 + ti) * HH + (j0 + tj)];
        tAT[ti][tj] = Ab[(size_t)(j0 + ti) * HH + (i0 + tj)];
        tAl[ti][tj] = alpha[(size_t)(i0 + ti) * HH + (j0 + tj)];
        if (t < TJ * DD) {
            int jj = t / DD, d = t % DD;
            th_j[jj][d] = theta[(b * HH + j0 + jj) * DD + d];
        }
        __syncthreads();

        float araw = 0.5f * (tA[ti][tj] + tAT[tj][ti]);
        float alat = araw > 0.f ? araw : 0.f;
        float al   = tAl[ti][tj];
        #pragma unroll
        for (int d = 0; d < DD; ++d) {
            float pd = th_j[tj][d] - my_thi[d] - al;
            acc[d] += alat * __sinf(pd);
        }
    }

    // reduce over tj within each 16-lane group (ti is lane-contiguous)
    #pragma unroll
    for (int d = 0; d < DD; ++d) {
        float v = acc[d];
        v += __shfl_down(v, 8, 16);
        v += __shfl_down(v, 4, 16);
        v += __shfl_down(v, 2, 16);
        v += __shfl_down(v, 1, 16);
        acc[d] = v;
    }

    if (tj == 0) {
        const int i = i0 + ti;
        const float g = gamma[b * HH + i];
        #pragma unroll
        for (int d = 0; d < DD; ++d) {
            float th   = my_thi[d];
            float coup = (1.0f / HH) * acc[d];   // K_COUP = 1
            float td   = omega[i * DD + d] + coup + kappa[i * DD + d] * (g - th);
            out[(b * HH + i) * DD + d] = th + td;   // DT = 1
        }
    }
}

extern "C" void kernel_launch(void* const* d_in, const int* in_sizes, int n_in,
                              void* d_out, int out_size, void* d_ws, size_t ws_size,
                              hipStream_t stream) {
    const float* theta = (const float*)d_in[0];
    const float* gamma = (const float*)d_in[1];
    const float* A     = (const float*)d_in[2];
    const float* omega = (const float*)d_in[3];
    const float* kappa = (const float*)d_in[4];
    const float* alpha = (const float*)d_in[5];
    float* out = (float*)d_out;

    dim3 grid(BB * (HH / TI));
    dim3 block(256);
    hipLaunchKernelGGL(kuramoto_kernel, grid, block, 0, stream,
                       theta, gamma, A, omega, kappa, alpha, out);
}

// Round 2
// 103.403 us; speedup vs baseline: 1.1793x; 1.1793x over previous
//
#include <hip/hip_runtime.h>
#include <math.h>

// Problem constants (from reference)
#define BB 8
#define HH 1024
#define DD 4
#define TI 16         // i-rows per block
#define JC 256        // j-chunk per block
#define NJC (HH / JC) // 4 j-chunks

// ws layout: float4 partial[NJC][BB][HH]  = 4*8*1024*16B = 512 KB

__global__ __launch_bounds__(256) void kuramoto_partial(
    const float* __restrict__ theta, const float* __restrict__ A,
    const float* __restrict__ alpha, float* __restrict__ ws)
{
    const int blk = blockIdx.x;          // (b * 64 + it) * NJC + jc  (b-major for L3 locality)
    const int jc  = blk & (NJC - 1);
    const int it  = (blk >> 2) & 63;
    const int b   = blk >> 8;
    const int i0  = it * TI;
    const int j0  = jc * JC;
    const int t   = threadIdx.x;
    const int ti  = t >> 4;              // 0..15
    const int tj  = t & 15;              // 0..15

    __shared__ float4 sThJ[JC];          // theta[b, j0+j, :] as float4   (4 KB)
    __shared__ float  sAT[JC][TI + 1];   // A[b, j0+j, i0+i] transposed   (17.4 KB)

    const float* Ab = A + (size_t)b * HH * HH;

    // stage theta_j: one float4 row per thread (coalesced)
    sThJ[t] = ((const float4*)theta)[(size_t)b * HH + j0 + t];

    // stage transposed A tile: 256 rows x 16 cols, coalesced float4 loads
    {
        const int r = t >> 2;            // 0..63
        const int c = (t & 3) * 4;       // 0,4,8,12
        #pragma unroll
        for (int rr = 0; rr < JC; rr += 64) {
            const int row = rr + r;
            const float4 v = *(const float4*)&Ab[(size_t)(j0 + row) * HH + i0 + c];
            sAT[row][c + 0] = v.x;
            sAT[row][c + 1] = v.y;
            sAT[row][c + 2] = v.z;
            sAT[row][c + 3] = v.w;
        }
    }
    __syncthreads();   // the only barrier

    const float4 thi   = ((const float4*)theta)[(size_t)b * HH + i0 + ti];
    const float* Arow  = Ab    + (size_t)(i0 + ti) * HH + j0;
    const float* alrow = alpha + (size_t)(i0 + ti) * HH + j0;

    float a0 = 0.f, a1 = 0.f, a2 = 0.f, a3 = 0.f;
    #pragma unroll
    for (int s = 0; s < JC / 16; ++s) {
        const int jj = tj + 16 * s;
        const float ad = Arow[jj];          // coalesced global (L1/L2)
        const float al = alrow[jj];         // coalesced global
        const float at = sAT[jj][ti];       // LDS, <=2-way conflict (free)
        const float alat = fmaxf(0.5f * (ad + at), 0.0f);
        const float4 thj = sThJ[jj];        // LDS broadcast-ish
        a0 += alat * __sinf(thj.x - thi.x - al);
        a1 += alat * __sinf(thj.y - thi.y - al);
        a2 += alat * __sinf(thj.z - thi.z - al);
        a3 += alat * __sinf(thj.w - thi.w - al);
    }

    // reduce over the 16 tj lanes (each ti group is lane-contiguous in a wave)
    #pragma unroll
    for (int off = 8; off >= 1; off >>= 1) {
        a0 += __shfl_down(a0, off, 16);
        a1 += __shfl_down(a1, off, 16);
        a2 += __shfl_down(a2, off, 16);
        a3 += __shfl_down(a3, off, 16);
    }

    if (tj == 0) {
        float4 r; r.x = a0; r.y = a1; r.z = a2; r.w = a3;
        ((float4*)ws)[((size_t)jc * BB + b) * HH + i0 + ti] = r;
    }
}

__global__ __launch_bounds__(256) void kuramoto_final(
    const float* __restrict__ theta, const float* __restrict__ gamma,
    const float* __restrict__ omega, const float* __restrict__ kappa,
    const float* __restrict__ ws, float* __restrict__ out)
{
    const int idx = blockIdx.x * 256 + threadIdx.x;   // (b,i) flat, 8192 total
    const int i   = idx & (HH - 1);
    const float4* w4 = (const float4*)ws;

    float4 p = w4[idx];                                // jc = 0 slice is [BB][HH] flat
    #pragma unroll
    for (int jc = 1; jc < NJC; ++jc) {
        const float4 q = w4[(size_t)jc * BB * HH + idx];
        p.x += q.x; p.y += q.y; p.z += q.z; p.w += q.w;
    }

    const float4 th = ((const float4*)theta)[idx];
    const float4 om = ((const float4*)omega)[i];
    const float4 kp = ((const float4*)kappa)[i];
    const float  g  = gamma[idx];
    const float  inv = 1.0f / HH;   // K_COUP = 1, DT = 1

    float4 o;
    o.x = th.x + om.x + p.x * inv + kp.x * (g - th.x);
    o.y = th.y + om.y + p.y * inv + kp.y * (g - th.y);
    o.z = th.z + om.z + p.z * inv + kp.z * (g - th.z);
    o.w = th.w + om.w + p.w * inv + kp.w * (g - th.w);
    ((float4*)out)[idx] = o;
}

extern "C" void kernel_launch(void* const* d_in, const int* in_sizes, int n_in,
                              void* d_out, int out_size, void* d_ws, size_t ws_size,
                              hipStream_t stream) {
    const float* theta = (const float*)d_in[0];
    const float* gamma = (const float*)d_in[1];
    const float* A     = (const float*)d_in[2];
    const float* omega = (const float*)d_in[3];
    const float* kappa = (const float*)d_in[4];
    const float* alpha = (const float*)d_in[5];
    float* out = (float*)d_out;
    float* ws  = (float*)d_ws;

    hipLaunchKernelGGL(kuramoto_partial, dim3(BB * (HH / TI) * NJC), dim3(256), 0, stream,
                       theta, A, alpha, ws);
    hipLaunchKernelGGL(kuramoto_final, dim3(BB * HH / 256), dim3(256), 0, stream,
                       theta, gamma, omega, kappa, ws, out);
}

// Round 3
// 93.179 us; speedup vs baseline: 1.3087x; 1.1097x over previous
//
#include <hip/hip_runtime.h>
#include <math.h>

// Problem constants (from reference)
#define BB 8
#define HH 1024
#define DD 4
#define TI 16            // i-rows per block
#define NJC 8            // j-chunks
#define JC (HH / NJC)    // 128 j per block

// ws layout: float4 partial[NJC][BB][HH] = 8*8*1024*16B = 1 MB

__global__ __launch_bounds__(256, 8) void kuramoto_partial(
    const float* __restrict__ theta, const float* __restrict__ A,
    const float* __restrict__ alpha, float* __restrict__ ws)
{
    const int blk = blockIdx.x;          // ((b*64 + it)*NJC + jc)
    const int jc  = blk & (NJC - 1);
    const int it  = (blk >> 3) & 63;
    const int b   = blk >> 9;
    const int i0  = it * TI;
    const int j0  = jc * JC;
    const int t   = threadIdx.x;
    const int ti  = t >> 4;              // 0..15
    const int tj  = t & 15;              // 0..15

    __shared__ float sTh0[JC], sTh1[JC], sTh2[JC], sTh3[JC];  // SoA theta_j planes (2 KB)
    __shared__ float sAT[JC][TI + 1];                         // A[b, j0+r, i0+c]  (8.7 KB)

    const float* Ab = A + (size_t)b * HH * HH;

    // stage theta_j SoA (threads 0..127, coalesced float4 reads)
    if (t < JC) {
        const float4 v = ((const float4*)theta)[(size_t)b * HH + j0 + t];
        sTh0[t] = v.x; sTh1[t] = v.y; sTh2[t] = v.z; sTh3[t] = v.w;
    }

    // stage transposed A tile: 128 rows x 16 cols, coalesced float4 loads
    {
        const int r = t >> 2;            // 0..63
        const int c = (t & 3) * 4;       // 0,4,8,12
        #pragma unroll
        for (int rr = 0; rr < JC; rr += 64) {
            const int row = rr + r;
            const float4 v = *(const float4*)&Ab[(size_t)(j0 + row) * HH + i0 + c];
            sAT[row][c + 0] = v.x;
            sAT[row][c + 1] = v.y;
            sAT[row][c + 2] = v.z;
            sAT[row][c + 3] = v.w;
        }
    }
    __syncthreads();   // the only barrier

    const float4 thi = ((const float4*)theta)[(size_t)b * HH + i0 + ti];
    const float4* Arow4  = (const float4*)(Ab    + (size_t)(i0 + ti) * HH + j0);
    const float4* alrow4 = (const float4*)(alpha + (size_t)(i0 + ti) * HH + j0);

    float a0 = 0.f, a1 = 0.f, a2 = 0.f, a3 = 0.f;

    #pragma unroll
    for (int s = 0; s < JC / 64; ++s) {          // 2 iters, 4 j's each
        const int q = tj + 16 * s;               // quad index
        const float4 ad = Arow4[q];              // coalesced b128 global
        const float4 al = alrow4[q];             // coalesced b128 global
        const int j = 4 * q;
        #pragma unroll
        for (int k = 0; k < 4; ++k) {
            const float adk = (&ad.x)[k];
            const float alk = (&al.x)[k];
            const float at  = sAT[j + k][ti];    // 2-way bank alias (free)
            const float alat = fmaxf(0.5f * (adk + at), 0.0f);
            a0 += alat * __sinf(sTh0[j + k] - thi.x - alk);
            a1 += alat * __sinf(sTh1[j + k] - thi.y - alk);
            a2 += alat * __sinf(sTh2[j + k] - thi.z - alk);
            a3 += alat * __sinf(sTh3[j + k] - thi.w - alk);
        }
    }

    // reduce over the 16 tj lanes (ti groups are lane-contiguous in a wave)
    #pragma unroll
    for (int off = 8; off >= 1; off >>= 1) {
        a0 += __shfl_down(a0, off, 16);
        a1 += __shfl_down(a1, off, 16);
        a2 += __shfl_down(a2, off, 16);
        a3 += __shfl_down(a3, off, 16);
    }

    if (tj == 0) {
        float4 r; r.x = a0; r.y = a1; r.z = a2; r.w = a3;
        ((float4*)ws)[((size_t)jc * BB + b) * HH + i0 + ti] = r;
    }
}

__global__ __launch_bounds__(256) void kuramoto_final(
    const float* __restrict__ theta, const float* __restrict__ gamma,
    const float* __restrict__ omega, const float* __restrict__ kappa,
    const float* __restrict__ ws, float* __restrict__ out)
{
    const int idx = blockIdx.x * 256 + threadIdx.x;   // (b,i) flat, 8192 total
    const int i   = idx & (HH - 1);
    const float4* w4 = (const float4*)ws;

    float4 p = w4[idx];
    #pragma unroll
    for (int jc = 1; jc < NJC; ++jc) {
        const float4 q = w4[(size_t)jc * BB * HH + idx];
        p.x += q.x; p.y += q.y; p.z += q.z; p.w += q.w;
    }

    const float4 th = ((const float4*)theta)[idx];
    const float4 om = ((const float4*)omega)[i];
    const float4 kp = ((const float4*)kappa)[i];
    const float  g  = gamma[idx];
    const float  inv = 1.0f / HH;   // K_COUP = 1, DT = 1

    float4 o;
    o.x = th.x + om.x + p.x * inv + kp.x * (g - th.x);
    o.y = th.y + om.y + p.y * inv + kp.y * (g - th.y);
    o.z = th.z + om.z + p.z * inv + kp.z * (g - th.z);
    o.w = th.w + om.w + p.w * inv + kp.w * (g - th.w);
    ((float4*)out)[idx] = o;
}

extern "C" void kernel_launch(void* const* d_in, const int* in_sizes, int n_in,
                              void* d_out, int out_size, void* d_ws, size_t ws_size,
                              hipStream_t stream) {
    const float* theta = (const float*)d_in[0];
    const float* gamma = (const float*)d_in[1];
    const float* A     = (const float*)d_in[2];
    const float* omega = (const float*)d_in[3];
    const float* kappa = (const float*)d_in[4];
    const float* alpha = (const float*)d_in[5];
    float* out = (float*)d_out;
    float* ws  = (float*)d_ws;

    hipLaunchKernelGGL(kuramoto_partial, dim3(BB * (HH / TI) * NJC), dim3(256), 0, stream,
                       theta, A, alpha, ws);
    hipLaunchKernelGGL(kuramoto_final, dim3(BB * HH / 256), dim3(256), 0, stream,
                       theta, gamma, omega, kappa, ws, out);
}